// Round 4
// baseline (254.021 us; speedup 1.0000x reference)
//
#include <hip/hip_runtime.h>
#include <stdint.h>

static constexpr int kN   = 50000;   // nodes
static constexpr int kCap = 64;      // adjacency capacity per node (Poisson(12) tail @64 ~ 1e-25)
static constexpr int kW2TBlocks = 16;    // 16*256 = 4096 = W2T dwords
static constexpr int kGemm1Blocks = 1564;  // 391 rb-groups x 4 rb x ... (782 groups x 2 cg)

typedef __attribute__((ext_vector_type(8))) _Float16 f16x8;  // MFMA A/B fragment
typedef __attribute__((ext_vector_type(2))) _Float16 f16x2;  // packed pair -> v_pk_add_f16
typedef __attribute__((ext_vector_type(4))) float f32x4;     // MFMA 16x16 accumulator

// ---------------- threefry2x32-20 (verified vs Random123 KAT) ----------------
__device__ __forceinline__ uint32_t rotl32(uint32_t v, uint32_t r) {
  return (v << r) | (v >> (32u - r));
}

__device__ __forceinline__ uint2 threefry2x32(uint32_t k0, uint32_t k1,
                                              uint32_t x0, uint32_t x1) {
  const uint32_t k2 = k0 ^ k1 ^ 0x1BD11BDAu;
  x0 += k0; x1 += k1;
#define TFR(r) { x0 += x1; x1 = rotl32(x1, r); x1 ^= x0; }
  TFR(13u) TFR(15u) TFR(26u) TFR(6u)
  x0 += k1; x1 += k2 + 1u;
  TFR(17u) TFR(29u) TFR(16u) TFR(24u)
  x0 += k2; x1 += k0 + 2u;
  TFR(13u) TFR(15u) TFR(26u) TFR(6u)
  x0 += k0; x1 += k1 + 3u;
  TFR(17u) TFR(29u) TFR(16u) TFR(24u)
  x0 += k1; x1 += k2 + 4u;
  TFR(13u) TFR(15u) TFR(26u) TFR(6u)
  x0 += k2; x1 += k0 + 5u;
#undef TFR
  return make_uint2(x0, x1);
}

__device__ __forceinline__ bool drop_elem(uint32_t j) {
  const uint2 r = threefry2x32(0u, 42u, 0u, j);
  return ((r.x ^ r.y) >> 31) != 0u;
}

// ---------------- f16 pack/unpack ----------------
union PairU { f16x2 h; uint32_t u; };
__device__ __forceinline__ uint32_t pack_f16x2(float lo, float hi) {
  PairU p; p.h[0] = (_Float16)lo; p.h[1] = (_Float16)hi; return p.u;
}
__device__ __forceinline__ float f16_lo(f16x2 v) { return (float)v[0]; }
__device__ __forceinline__ float f16_hi(f16x2 v) { return (float)v[1]; }

union FragU { uint4 q; f16x8 f; };

// z1 is stored PASS-MAJOR: z1q[p][node][16 dwords], p=0..3 (3.2 MB per pass --
// fits a 4 MB per-XCD L2 so the K2 gather working set is L2-resident).
// Dword d of a node's 64-dword feature row (features 2d,2d+1) lives at
// z1q[((d>>4)*kN + node)*16 + (d&15)]. Same scheme for z2 with 2 passes.

// ---------------- K1: adj-build | W2T-pack | gemm1 (block-range split) ----------------
__global__ __launch_bounds__(256, 8) void k1_adj_w2t_gemm1(
    const float* __restrict__ x, const float* __restrict__ W1,
    const float* __restrict__ W2, uint32_t* __restrict__ W2T,
    const int* __restrict__ src, const int* __restrict__ dst,
    int* __restrict__ cnt, int* __restrict__ adj, int E, int adjBlocks,
    uint32_t* __restrict__ z1q) {
  __shared__ uint32_t WT[64 * 64];  // 16 KB, fragment-major (gemm1 region only)

  if (blockIdx.x < adjBlocks) {
    const int base = blockIdx.x * 1024 + threadIdx.x;
    int d[4], s[4];
    bool ok[4];
#pragma unroll
    for (int j = 0; j < 4; ++j) {
      const int e = base + j * 256;
      ok[j] = (e < E);
      d[j] = ok[j] ? dst[e] : 0;
      s[j] = ok[j] ? src[e] : 0;
    }
    int slot[4];
#pragma unroll
    for (int j = 0; j < 4; ++j)
      slot[j] = ok[j] ? atomicAdd(&cnt[d[j]], 1) : kCap;
#pragma unroll
    for (int j = 0; j < 4; ++j)
      if (ok[j] && slot[j] < kCap) adj[d[j] * kCap + slot[j]] = s[j];
    return;
  }

  if (blockIdx.x < adjBlocks + kW2TBlocks) {
    const int w = (blockIdx.x - adjBlocks) * 256 + threadIdx.x;  // < 4096
    const int n = w >> 6, i = w & 63;
    W2T[w] = pack_f16x2(W2[(size_t)(2 * i) * 64 + n], W2[(size_t)(2 * i + 1) * 64 + n]);
    return;
  }

  // ---- gemm1 region ----
  const int gb = blockIdx.x - adjBlocks - kW2TBlocks;  // 0..1563
  const int cg = gb & 1;                               // column group: cols cg*64..+63

  // Stage this cg's half of W1, fragment-major (conflict-free B-fragment reads).
  for (int v = threadIdx.x; v < 64 * 64; v += 256) {
    const int i  = v >> 6;        // k-pair index 0..63
    const int nl = v & 63;        // local column 0..63
    const int kb = i >> 4, r = i & 15;
    const int quad_s = r >> 2, c = r & 3;
    const int ct = nl >> 4, mrow_s = nl & 15;
    const int n = cg * 64 + nl;
    WT[((ct * 4 + kb) * 4 + quad_s) * 64 + mrow_s * 4 + c] =
        pack_f16x2(W1[(size_t)(2 * i) * 128 + n], W1[(size_t)(2 * i + 1) * 128 + n]);
  }
  __syncthreads();

  const int lane = threadIdx.x & 63;
  const int wid  = threadIdx.x >> 6;
  const int rb   = (gb >> 1) * 4 + wid;  // -> rb 0..3127
  if (rb >= 3125) return;                // tail wave (after barrier)
  const int n0   = rb * 16;
  const int quad = lane >> 4;
  const int mrow = lane & 15;

  const float* xp = x + (size_t)(n0 + mrow) * 128 + quad * 8;
  f32x4 acc[4] = {{0.f,0.f,0.f,0.f},{0.f,0.f,0.f,0.f},{0.f,0.f,0.f,0.f},{0.f,0.f,0.f,0.f}};

#pragma unroll
  for (int kb = 0; kb < 4; ++kb) {
    const float4 lo = *reinterpret_cast<const float4*>(xp + kb * 32);
    const float4 hi = *reinterpret_cast<const float4*>(xp + kb * 32 + 4);
    FragU a;
    a.q = make_uint4(pack_f16x2(lo.x, lo.y), pack_f16x2(lo.z, lo.w),
                     pack_f16x2(hi.x, hi.y), pack_f16x2(hi.z, hi.w));
#pragma unroll
    for (int ct = 0; ct < 4; ++ct) {
      FragU b;
      b.q = *reinterpret_cast<const uint4*>(&WT[((ct * 4 + kb) * 4 + quad) * 64 + mrow * 4]);
      acc[ct] = __builtin_amdgcn_mfma_f32_16x16x32_f16(a.f, b.f, acc[ct], 0, 0, 0);
    }
  }

#pragma unroll
  for (int ct = 0; ct < 4; ++ct) {
#pragma unroll
    for (int r = 0; r < 4; ++r) {
      const float v = acc[ct][r];
      const float vOdd = __shfl(v, lane | 1);
      if ((lane & 1) == 0) {
        const int row = n0 + quad * 4 + r;
        const int d = cg * 32 + ct * 8 + (mrow >> 1);   // row dword 0..63
        z1q[((size_t)(d >> 4) * kN + row) * 16 + (d & 15)] = pack_f16x2(v, vOdd);
      }
    }
  }
}

// ---------------- K2: agg1 (pass-split gather) + gemm2 fused ----------------
// Per wave: 2 nodes; adjacency rows held in registers across all 4 feature
// passes. Lane = group(lane>>4) x featdword(lane&15): one load instruction
// gathers 4 neighbors' 64B pass-rows (4x64B lines, fully used, L2-resident).
// Group partial sums are reduced with shfl_xor(16/32). h goes to LDS, then
// each wave runs one 16-col tile of z2 = h @ W2.
__global__ __launch_bounds__(256, 8) void agg1_gemm2(
    const uint32_t* __restrict__ z1q, const int* __restrict__ adj,
    const int* __restrict__ cnt, const float* __restrict__ b1,
    const uint32_t* __restrict__ zdw, const uint32_t* __restrict__ W2T,
    uint32_t* __restrict__ z2q) {
  __shared__ uint32_t WT[64 * 68];  // 17.4 KB W2 packed
  __shared__ uint32_t HT[8 * 68];   // 2.2 KB h-tile (8 rows/block)

  // Stage W2T linearly (conflict-free); consumed only after the post-agg barrier.
  for (int v = threadIdx.x; v < 64 * 64; v += 256)
    WT[(v >> 6) * 68 + (v & 63)] = W2T[v];

  const int lane = threadIdx.x & 63;
  const int wid  = threadIdx.x >> 6;
  const int n0   = blockIdx.x * 8;       // 6250 blocks * 8 nodes
  const int nA = n0 + 2 * wid, nB = nA + 1;
  const int g  = lane >> 4;   // neighbor group 0..3
  const int fl = lane & 15;   // feature dword within 64B pass-row

  const int vaA = adj[(size_t)nA * kCap + lane];
  const int vaB = adj[(size_t)nB * kCap + lane];
  int dA = __builtin_amdgcn_readfirstlane(cnt[nA]); if (dA > kCap) dA = kCap;
  int dB = __builtin_amdgcn_readfirstlane(cnt[nB]); if (dB > kCap) dB = kCap;
  const int dm = (dA > dB) ? dA : dB;

#pragma unroll
  for (int p = 0; p < 4; ++p) {
    const uint32_t* baseP = z1q + (size_t)p * kN * 16;
    // self: counted once (group 0 only; other groups read zeroed pad)
    const uint32_t* sa = (g == 0) ? (baseP + (size_t)nA * 16) : zdw;
    const uint32_t* sb = (g == 0) ? (baseP + (size_t)nB * 16) : zdw;
    PairU aA0, aA1, aB0, aB1;
    aA0.u = sa[fl]; aB0.u = sb[fl]; aA1.u = 0u; aB1.u = 0u;

    for (int e = 0; e < dm; e += 16) {
      uint32_t lA[4], lB[4];
#pragma unroll
      for (int j = 0; j < 4; ++j) {
        const int e0 = e + j * 4;
        const int i0 = __builtin_amdgcn_readlane(vaA, e0);
        const int i1 = __builtin_amdgcn_readlane(vaA, e0 + 1);
        const int i2 = __builtin_amdgcn_readlane(vaA, e0 + 2);
        const int i3 = __builtin_amdgcn_readlane(vaA, e0 + 3);
        const int idx = (g & 2) ? ((g & 1) ? i3 : i2) : ((g & 1) ? i1 : i0);
        const uint32_t* ba = (e0 + g < dA) ? (baseP + (size_t)idx * 16) : zdw;
        lA[j] = ba[fl];
      }
#pragma unroll
      for (int j = 0; j < 4; ++j) {
        const int e0 = e + j * 4;
        const int i0 = __builtin_amdgcn_readlane(vaB, e0);
        const int i1 = __builtin_amdgcn_readlane(vaB, e0 + 1);
        const int i2 = __builtin_amdgcn_readlane(vaB, e0 + 2);
        const int i3 = __builtin_amdgcn_readlane(vaB, e0 + 3);
        const int idx = (g & 2) ? ((g & 1) ? i3 : i2) : ((g & 1) ? i1 : i0);
        const uint32_t* bb = (e0 + g < dB) ? (baseP + (size_t)idx * 16) : zdw;
        lB[j] = bb[fl];
      }
#pragma unroll
      for (int j = 0; j < 4; ++j) {
        PairU t; t.u = lA[j];
        PairU u; u.u = lB[j];
        if (j & 1) { aA1.h += t.h; aB1.h += u.h; }
        else       { aA0.h += t.h; aB0.h += u.h; }
      }
    }

    // reduce the 4 neighbor-groups (after this, every lane holds the full sum
    // for its feature dword)
    PairU sA; sA.h = aA0.h + aA1.h;
    PairU sB; sB.h = aB0.h + aB1.h;
    PairU t;
    t.u = (uint32_t)__shfl_xor((int)sA.u, 16); sA.h += t.h;
    t.u = (uint32_t)__shfl_xor((int)sA.u, 32); sA.h += t.h;
    t.u = (uint32_t)__shfl_xor((int)sB.u, 16); sB.h += t.h;
    t.u = (uint32_t)__shfl_xor((int)sB.u, 32); sB.h += t.h;

    const int d = p * 16 + fl;  // row dword 0..63 (features 2d, 2d+1)
    const float2 bb2 = *reinterpret_cast<const float2*>(b1 + 2 * d);
    {
      float hx = fmaxf(f16_lo(sA.h) + bb2.x, 0.0f);
      float hy = fmaxf(f16_hi(sA.h) + bb2.y, 0.0f);
      const uint32_t j0 = (uint32_t)nA * 128u + 2u * (uint32_t)d;
      hx = drop_elem(j0)      ? 0.0f : hx * 2.0f;
      hy = drop_elem(j0 + 1u) ? 0.0f : hy * 2.0f;
      if (lane < 16) HT[(2 * wid) * 68 + d] = pack_f16x2(hx, hy);
    }
    {
      float hx = fmaxf(f16_lo(sB.h) + bb2.x, 0.0f);
      float hy = fmaxf(f16_hi(sB.h) + bb2.y, 0.0f);
      const uint32_t j0 = (uint32_t)nB * 128u + 2u * (uint32_t)d;
      hx = drop_elem(j0)      ? 0.0f : hx * 2.0f;
      hy = drop_elem(j0 + 1u) ? 0.0f : hy * 2.0f;
      if (lane < 16) HT[(2 * wid + 1) * 68 + d] = pack_f16x2(hx, hy);
    }
  }
  __syncthreads();

  // ---- gemm2 phase: wave wid computes output cols [wid*16, wid*16+16) for
  // the block's 8 rows. A-fragment rows 8-15 clamped to 0-7 (outputs unwritten).
  const int quad = lane >> 4;
  const int mrow = lane & 15;
  const int ct   = wid;
  f32x4 acc = {0.f, 0.f, 0.f, 0.f};
#pragma unroll
  for (int kb = 0; kb < 4; ++kb) {
    FragU a;
    a.q = *reinterpret_cast<const uint4*>(&HT[(mrow & 7) * 68 + kb * 16 + quad * 4]);
    FragU b;
    b.q = *reinterpret_cast<const uint4*>(&WT[(ct * 16 + mrow) * 68 + kb * 16 + quad * 4]);
    acc = __builtin_amdgcn_mfma_f32_16x16x32_f16(a.f, b.f, acc, 0, 0, 0);
  }
#pragma unroll
  for (int r = 0; r < 4; ++r) {
    const float v = acc[r];
    const float vOdd = __shfl(v, lane | 1);
    const int rloc = quad * 4 + r;                 // D row = quad*4+reg
    if ((lane & 1) == 0 && rloc < 8) {
      const int d2 = ct * 8 + (mrow >> 1);         // z2 row dword 0..31
      z2q[((size_t)(d2 >> 4) * kN + (n0 + rloc)) * 16 + (d2 & 15)] = pack_f16x2(v, vOdd);
    }
  }
}

// ---------------- agg_out: out = z2[n] + sum z2[adj] + b2 (pass-split gather) ----
// Same 4-neighbor-group gather as K2, 2 passes of 64B pass-rows (3.2 MB each,
// L2-resident). Output written directly as float2 by lanes 0..15.
__global__ __launch_bounds__(256, 8) void agg_out(
    const uint32_t* __restrict__ z2q, const int* __restrict__ adj,
    const int* __restrict__ cnt, const float* __restrict__ b2,
    const uint32_t* __restrict__ zdw, float* __restrict__ out) {
  const int lane = threadIdx.x & 63;
  const int wid  = threadIdx.x >> 6;
  const int pp = blockIdx.x * 4 + wid;   // 6250 blocks
  const int nA = pp * 2, nB = pp * 2 + 1;
  const int g  = lane >> 4;
  const int fl = lane & 15;

  const int vaA = adj[(size_t)nA * kCap + lane];
  const int vaB = adj[(size_t)nB * kCap + lane];
  int dA = __builtin_amdgcn_readfirstlane(cnt[nA]); if (dA > kCap) dA = kCap;
  int dB = __builtin_amdgcn_readfirstlane(cnt[nB]); if (dB > kCap) dB = kCap;
  const int dm = (dA > dB) ? dA : dB;

#pragma unroll
  for (int p = 0; p < 2; ++p) {
    const uint32_t* baseP = z2q + (size_t)p * kN * 16;
    const uint32_t* sa = (g == 0) ? (baseP + (size_t)nA * 16) : zdw;
    const uint32_t* sb = (g == 0) ? (baseP + (size_t)nB * 16) : zdw;
    PairU aA0, aA1, aB0, aB1;
    aA0.u = sa[fl]; aB0.u = sb[fl]; aA1.u = 0u; aB1.u = 0u;

    for (int e = 0; e < dm; e += 16) {
      uint32_t lA[4], lB[4];
#pragma unroll
      for (int j = 0; j < 4; ++j) {
        const int e0 = e + j * 4;
        const int i0 = __builtin_amdgcn_readlane(vaA, e0);
        const int i1 = __builtin_amdgcn_readlane(vaA, e0 + 1);
        const int i2 = __builtin_amdgcn_readlane(vaA, e0 + 2);
        const int i3 = __builtin_amdgcn_readlane(vaA, e0 + 3);
        const int idx = (g & 2) ? ((g & 1) ? i3 : i2) : ((g & 1) ? i1 : i0);
        const uint32_t* ba = (e0 + g < dA) ? (baseP + (size_t)idx * 16) : zdw;
        lA[j] = ba[fl];
      }
#pragma unroll
      for (int j = 0; j < 4; ++j) {
        const int e0 = e + j * 4;
        const int i0 = __builtin_amdgcn_readlane(vaB, e0);
        const int i1 = __builtin_amdgcn_readlane(vaB, e0 + 1);
        const int i2 = __builtin_amdgcn_readlane(vaB, e0 + 2);
        const int i3 = __builtin_amdgcn_readlane(vaB, e0 + 3);
        const int idx = (g & 2) ? ((g & 1) ? i3 : i2) : ((g & 1) ? i1 : i0);
        const uint32_t* bb = (e0 + g < dB) ? (baseP + (size_t)idx * 16) : zdw;
        lB[j] = bb[fl];
      }
#pragma unroll
      for (int j = 0; j < 4; ++j) {
        PairU t; t.u = lA[j];
        PairU u; u.u = lB[j];
        if (j & 1) { aA1.h += t.h; aB1.h += u.h; }
        else       { aA0.h += t.h; aB0.h += u.h; }
      }
    }

    PairU sA; sA.h = aA0.h + aA1.h;
    PairU sB; sB.h = aB0.h + aB1.h;
    PairU t;
    t.u = (uint32_t)__shfl_xor((int)sA.u, 16); sA.h += t.h;
    t.u = (uint32_t)__shfl_xor((int)sA.u, 32); sA.h += t.h;
    t.u = (uint32_t)__shfl_xor((int)sB.u, 16); sB.h += t.h;
    t.u = (uint32_t)__shfl_xor((int)sB.u, 32); sB.h += t.h;

    const int d = p * 16 + fl;  // z2 row dword 0..31 (features 2d, 2d+1)
    const float2 bb2 = *reinterpret_cast<const float2*>(b2 + 2 * d);
    if (lane < 16) {
      float2 oA; oA.x = f16_lo(sA.h) + bb2.x; oA.y = f16_hi(sA.h) + bb2.y;
      *reinterpret_cast<float2*>(out + (size_t)nA * 64 + 2 * d) = oA;
      float2 oB; oB.x = f16_lo(sB.h) + bb2.x; oB.y = f16_hi(sB.h) + bb2.y;
      *reinterpret_cast<float2*>(out + (size_t)nB * 64 + 2 * d) = oB;
    }
  }
}

// ---------------- launch ----------------
extern "C" void kernel_launch(void* const* d_in, const int* in_sizes, int n_in,
                              void* d_out, int out_size, void* d_ws, size_t ws_size,
                              hipStream_t stream) {
  const float* x  = (const float*)d_in[0];
  const int*   ei = (const int*)d_in[1];
  const float* W1 = (const float*)d_in[2];
  const float* b1 = (const float*)d_in[3];
  const float* W2 = (const float*)d_in[4];
  const float* b2 = (const float*)d_in[5];
  float* out = (float*)d_out;

  const int E = in_sizes[1] / 2;  // edge_index is (2, E), int32 on device
  const int* src = ei;
  const int* dst = ei + E;

  // d_ws layout:
  uint32_t* zpad = (uint32_t*)d_ws;                        // 64 dwords = 256 B, zeroed
  int*      cnt  = (int*)((char*)d_ws + 256);              // 50000 ints
  int*      adj  = cnt + kN;                               // 50000*64 ints = 12.8 MB
  uint32_t* z1q  = (uint32_t*)(adj + (size_t)kN * kCap);   // 4 passes x 50000 x 16 dwords = 12.8 MB
  uint32_t* z2q  = z1q + (size_t)kN * 64;                  // 2 passes x 50000 x 16 dwords = 6.4 MB
  uint32_t* W2T  = z2q + (size_t)kN * 32;                  // 4096 dwords = 16 KB

  const int adjBlocks = (E + 1023) / 1024;  // 4 edges/thread

  hipMemsetAsync(d_ws, 0, 256 + (size_t)kN * sizeof(int), stream);  // zpad + cnt
  k1_adj_w2t_gemm1<<<adjBlocks + kW2TBlocks + kGemm1Blocks, 256, 0, stream>>>(
      x, W1, W2, W2T, src, dst, cnt, adj, E, adjBlocks, z1q);
  agg1_gemm2<<<6250, 256, 0, stream>>>(
      z1q, adj, cnt, b1, zpad, W2T, z2q);
  agg_out<<<6250, 256, 0, stream>>>(
      z2q, adj, cnt, b2, zpad, out);
}

// Round 5
// 178.272 us; speedup vs baseline: 1.4249x; 1.4249x over previous
//
#include <hip/hip_runtime.h>
#include <stdint.h>

static constexpr int kN   = 50000;   // nodes
static constexpr int kCap = 64;      // adjacency capacity per node (Poisson(12) tail @64 ~ 1e-25)
static constexpr int kW2TBlocks = 16;    // 16*256 = 4096 = W2T dwords
static constexpr int kGemm1Blocks = 1564;  // 782 rb-groups x 2 cg

typedef __attribute__((ext_vector_type(8))) _Float16 f16x8;  // MFMA A/B fragment
typedef __attribute__((ext_vector_type(2))) _Float16 f16x2;  // packed pair -> v_pk_add_f16
typedef __attribute__((ext_vector_type(4))) float f32x4;     // MFMA 16x16 accumulator

// ---------------- threefry2x32-20 (verified vs Random123 KAT) ----------------
__device__ __forceinline__ uint32_t rotl32(uint32_t v, uint32_t r) {
  return (v << r) | (v >> (32u - r));
}

__device__ __forceinline__ uint2 threefry2x32(uint32_t k0, uint32_t k1,
                                              uint32_t x0, uint32_t x1) {
  const uint32_t k2 = k0 ^ k1 ^ 0x1BD11BDAu;
  x0 += k0; x1 += k1;
#define TFR(r) { x0 += x1; x1 = rotl32(x1, r); x1 ^= x0; }
  TFR(13u) TFR(15u) TFR(26u) TFR(6u)
  x0 += k1; x1 += k2 + 1u;
  TFR(17u) TFR(29u) TFR(16u) TFR(24u)
  x0 += k2; x1 += k0 + 2u;
  TFR(13u) TFR(15u) TFR(26u) TFR(6u)
  x0 += k0; x1 += k1 + 3u;
  TFR(17u) TFR(29u) TFR(16u) TFR(24u)
  x0 += k1; x1 += k2 + 4u;
  TFR(13u) TFR(15u) TFR(26u) TFR(6u)
  x0 += k2; x1 += k0 + 5u;
#undef TFR
  return make_uint2(x0, x1);
}

__device__ __forceinline__ bool drop_elem(uint32_t j) {
  const uint2 r = threefry2x32(0u, 42u, 0u, j);
  return ((r.x ^ r.y) >> 31) != 0u;
}

// ---------------- f16 pack/unpack ----------------
union PairU { f16x2 h; uint32_t u; };
__device__ __forceinline__ uint32_t pack_f16x2(float lo, float hi) {
  PairU p; p.h[0] = (_Float16)lo; p.h[1] = (_Float16)hi; return p.u;
}
__device__ __forceinline__ float f16_lo(f16x2 v) { return (float)v[0]; }
__device__ __forceinline__ float f16_hi(f16x2 v) { return (float)v[1]; }

__device__ __forceinline__ void pk_acc(uint32_t& acc, uint32_t v) {
  PairU a, b; a.u = acc; b.u = v; a.h += b.h; acc = a.u;
}

union FragU { uint4 q; f16x8 f; };

// ---------------- K1: adj-build | W2T-pack | gemm1 (block-range split) ----------------
// Blocks [0, adjBlocks): adjacency build, 4 edges/thread (independent atomic chains).
// Blocks [adjBlocks, adjBlocks+16): W2T pack.
// Blocks [adjBlocks+16, ...): gemm1 z1h = pack_f16(x @ W1), 16 KB fragment-major
// LDS (conflict-free B-fragment reads), 8 blocks/CU.
__global__ __launch_bounds__(256, 8) void k1_adj_w2t_gemm1(
    const float* __restrict__ x, const float* __restrict__ W1,
    const float* __restrict__ W2, uint32_t* __restrict__ W2T,
    const int* __restrict__ src, const int* __restrict__ dst,
    int* __restrict__ cnt, int* __restrict__ adj, int E, int adjBlocks,
    uint32_t* __restrict__ z1h) {
  __shared__ uint32_t WT[64 * 64];  // 16 KB, fragment-major (gemm1 region only)

  if (blockIdx.x < adjBlocks) {
    const int base = blockIdx.x * 1024 + threadIdx.x;
    int d[4], s[4];
    bool ok[4];
#pragma unroll
    for (int j = 0; j < 4; ++j) {
      const int e = base + j * 256;
      ok[j] = (e < E);
      d[j] = ok[j] ? dst[e] : 0;
      s[j] = ok[j] ? src[e] : 0;
    }
    int slot[4];
#pragma unroll
    for (int j = 0; j < 4; ++j)
      slot[j] = ok[j] ? atomicAdd(&cnt[d[j]], 1) : kCap;
#pragma unroll
    for (int j = 0; j < 4; ++j)
      if (ok[j] && slot[j] < kCap) adj[d[j] * kCap + slot[j]] = s[j];
    return;
  }

  if (blockIdx.x < adjBlocks + kW2TBlocks) {
    const int w = (blockIdx.x - adjBlocks) * 256 + threadIdx.x;  // < 4096
    const int n = w >> 6, i = w & 63;
    W2T[w] = pack_f16x2(W2[(size_t)(2 * i) * 64 + n], W2[(size_t)(2 * i + 1) * 64 + n]);
    return;
  }

  // ---- gemm1 region ----
  const int gb = blockIdx.x - adjBlocks - kW2TBlocks;  // 0..1563
  const int cg = gb & 1;                               // column group: cols cg*64..+63

  // Stage this cg's half of W1, fragment-major (conflict-free B-fragment reads).
  for (int v = threadIdx.x; v < 64 * 64; v += 256) {
    const int i  = v >> 6;        // k-pair index 0..63
    const int nl = v & 63;        // local column 0..63
    const int kb = i >> 4, r = i & 15;
    const int quad_s = r >> 2, c = r & 3;
    const int ct = nl >> 4, mrow_s = nl & 15;
    const int n = cg * 64 + nl;
    WT[((ct * 4 + kb) * 4 + quad_s) * 64 + mrow_s * 4 + c] =
        pack_f16x2(W1[(size_t)(2 * i) * 128 + n], W1[(size_t)(2 * i + 1) * 128 + n]);
  }
  __syncthreads();

  const int lane = threadIdx.x & 63;
  const int wid  = threadIdx.x >> 6;
  const int rb   = (gb >> 1) * 4 + wid;  // -> rb 0..3127
  if (rb >= 3125) return;                // tail wave (after barrier)
  const int n0   = rb * 16;
  const int quad = lane >> 4;
  const int mrow = lane & 15;

  const float* xp = x + (size_t)(n0 + mrow) * 128 + quad * 8;
  f32x4 acc[4] = {{0.f,0.f,0.f,0.f},{0.f,0.f,0.f,0.f},{0.f,0.f,0.f,0.f},{0.f,0.f,0.f,0.f}};

#pragma unroll
  for (int kb = 0; kb < 4; ++kb) {
    const float4 lo = *reinterpret_cast<const float4*>(xp + kb * 32);
    const float4 hi = *reinterpret_cast<const float4*>(xp + kb * 32 + 4);
    FragU a;
    a.q = make_uint4(pack_f16x2(lo.x, lo.y), pack_f16x2(lo.z, lo.w),
                     pack_f16x2(hi.x, hi.y), pack_f16x2(hi.z, hi.w));
#pragma unroll
    for (int ct = 0; ct < 4; ++ct) {
      FragU b;
      b.q = *reinterpret_cast<const uint4*>(&WT[((ct * 4 + kb) * 4 + quad) * 64 + mrow * 4]);
      acc[ct] = __builtin_amdgcn_mfma_f32_16x16x32_f16(a.f, b.f, acc[ct], 0, 0, 0);
    }
  }

#pragma unroll
  for (int ct = 0; ct < 4; ++ct) {
#pragma unroll
    for (int r = 0; r < 4; ++r) {
      const float v = acc[ct][r];
      const float vOdd = __shfl(v, lane | 1);
      if ((lane & 1) == 0) {
        const int row = n0 + quad * 4 + r;
        z1h[(size_t)row * 64 + cg * 32 + ct * 8 + (mrow >> 1)] = pack_f16x2(v, vOdd);
      }
    }
  }
}

// ---------------- K2: agg1 (grouped dwordx4 gather) + gemm2 fused ----------------
// 2 nodes/wave. Lane = (group g=lane>>4, chunk fl=lane&15): ONE dwordx4 load
// covers 4 neighbors' full 256B rows (16 lanes x 16B each) -> 4x fewer VMEM
// instrs + addr calcs vs scalar-dword gather; neighbor index distributed by a
// single variable-lane shuffle. Cross-group combine: shfl_xor(16/32) per
// accumulator dword at loop end. Same bytes/lines as the verified layout.
__global__ __launch_bounds__(256, 8) void agg1_gemm2(
    const uint32_t* __restrict__ z1h, const int* __restrict__ adj,
    const int* __restrict__ cnt, const float* __restrict__ b1,
    const uint32_t* __restrict__ zpad, const uint32_t* __restrict__ W2T,
    uint32_t* __restrict__ z2h) {
  __shared__ uint32_t WT[64 * 68];  // 17.4 KB W2 packed
  __shared__ uint32_t HT[8 * 68];   // 2.2 KB h-tile (8 rows/block)

  // Stage W2T linearly (conflict-free); consumed only after the post-agg barrier.
  for (int v = threadIdx.x; v < 64 * 64; v += 256)
    WT[(v >> 6) * 68 + (v & 63)] = W2T[v];

  const int lane = threadIdx.x & 63;
  const int wid  = threadIdx.x >> 6;
  const int n0   = blockIdx.x * 8;       // 6250 blocks * 8 nodes
  const int nA = n0 + 2 * wid, nB = nA + 1;
  const int g  = lane >> 4;   // neighbor group 0..3
  const int fl = lane & 15;   // 16B chunk within 256B row

  const uint4* zq = reinterpret_cast<const uint4*>(zpad);

  const int vaA = adj[(size_t)nA * kCap + lane];
  const int vaB = adj[(size_t)nB * kCap + lane];
  int dA = __builtin_amdgcn_readfirstlane(cnt[nA]); if (dA > kCap) dA = kCap;
  int dB = __builtin_amdgcn_readfirstlane(cnt[nB]); if (dB > kCap) dB = kCap;
  const int dm = (dA > dB) ? dA : dB;

  uint32_t aA[4], aB[4];
  {  // self: group 0 loads the node's own row, other groups read zeroed pad
    const uint4* pa = (g == 0) ? reinterpret_cast<const uint4*>(z1h + (size_t)nA * 64) : zq;
    const uint4* pb = (g == 0) ? reinterpret_cast<const uint4*>(z1h + (size_t)nB * 64) : zq;
    const uint4 va = pa[fl];
    const uint4 vb = pb[fl];
    aA[0] = va.x; aA[1] = va.y; aA[2] = va.z; aA[3] = va.w;
    aB[0] = vb.x; aB[1] = vb.y; aB[2] = vb.z; aB[3] = vb.w;
  }

  for (int e = 0; e < dm; e += 16) {
    uint4 lA[4], lB[4];
#pragma unroll
    for (int j = 0; j < 4; ++j) {
      const int sl = e + j * 4 + g;                 // neighbor slot for this lane
      const int ia = __shfl(vaA, sl);               // one bpermute distributes 4 ids
      const uint4* pa = (sl < dA) ? reinterpret_cast<const uint4*>(z1h + (size_t)ia * 64) : zq;
      lA[j] = pa[fl];
    }
#pragma unroll
    for (int j = 0; j < 4; ++j) {
      const int sl = e + j * 4 + g;
      const int ib = __shfl(vaB, sl);
      const uint4* pb = (sl < dB) ? reinterpret_cast<const uint4*>(z1h + (size_t)ib * 64) : zq;
      lB[j] = pb[fl];
    }
#pragma unroll
    for (int j = 0; j < 4; ++j) {
      pk_acc(aA[0], lA[j].x); pk_acc(aA[1], lA[j].y);
      pk_acc(aA[2], lA[j].z); pk_acc(aA[3], lA[j].w);
      pk_acc(aB[0], lB[j].x); pk_acc(aB[1], lB[j].y);
      pk_acc(aB[2], lB[j].z); pk_acc(aB[3], lB[j].w);
    }
  }

  // cross-group reduce (lanes differing in bits 4/5 = other neighbor groups)
#pragma unroll
  for (int c = 0; c < 4; ++c) {
    uint32_t t;
    t = (uint32_t)__shfl_xor((int)aA[c], 16); pk_acc(aA[c], t);
    t = (uint32_t)__shfl_xor((int)aA[c], 32); pk_acc(aA[c], t);
    t = (uint32_t)__shfl_xor((int)aB[c], 16); pk_acc(aB[c], t);
    t = (uint32_t)__shfl_xor((int)aB[c], 32); pk_acc(aB[c], t);
  }

  // each lane owns row-dword d = 4*fl + g (all 64 dwords covered exactly once)
  const int d = 4 * fl + g;
  const uint32_t mA = (g & 2) ? ((g & 1) ? aA[3] : aA[2]) : ((g & 1) ? aA[1] : aA[0]);
  const uint32_t mB = (g & 2) ? ((g & 1) ? aB[3] : aB[2]) : ((g & 1) ? aB[1] : aB[0]);
  const float2 bb2 = *reinterpret_cast<const float2*>(b1 + 2 * d);
  {
    PairU s; s.u = mA;
    float hx = fmaxf(f16_lo(s.h) + bb2.x, 0.0f);
    float hy = fmaxf(f16_hi(s.h) + bb2.y, 0.0f);
    const uint32_t j0 = (uint32_t)nA * 128u + 2u * (uint32_t)d;
    hx = drop_elem(j0)      ? 0.0f : hx * 2.0f;
    hy = drop_elem(j0 + 1u) ? 0.0f : hy * 2.0f;
    HT[(2 * wid) * 68 + d] = pack_f16x2(hx, hy);   // 64 distinct dwords: <=2 lanes/bank
  }
  {
    PairU s; s.u = mB;
    float hx = fmaxf(f16_lo(s.h) + bb2.x, 0.0f);
    float hy = fmaxf(f16_hi(s.h) + bb2.y, 0.0f);
    const uint32_t j0 = (uint32_t)nB * 128u + 2u * (uint32_t)d;
    hx = drop_elem(j0)      ? 0.0f : hx * 2.0f;
    hy = drop_elem(j0 + 1u) ? 0.0f : hy * 2.0f;
    HT[(2 * wid + 1) * 68 + d] = pack_f16x2(hx, hy);
  }
  __syncthreads();

  // ---- gemm2 phase: wave wid computes output cols [wid*16, wid*16+16) for
  // the block's 8 rows. A-fragment rows 8-15 clamped to 0-7 (outputs unwritten).
  const int quad = lane >> 4;
  const int mrow = lane & 15;
  const int ct   = wid;
  f32x4 acc = {0.f, 0.f, 0.f, 0.f};
#pragma unroll
  for (int kb = 0; kb < 4; ++kb) {
    FragU a;
    a.q = *reinterpret_cast<const uint4*>(&HT[(mrow & 7) * 68 + kb * 16 + quad * 4]);
    FragU b;
    b.q = *reinterpret_cast<const uint4*>(&WT[(ct * 16 + mrow) * 68 + kb * 16 + quad * 4]);
    acc = __builtin_amdgcn_mfma_f32_16x16x32_f16(a.f, b.f, acc, 0, 0, 0);
  }
#pragma unroll
  for (int r = 0; r < 4; ++r) {
    const float v = acc[r];
    const float vOdd = __shfl(v, lane | 1);
    const int rloc = quad * 4 + r;                 // D row = quad*4+reg
    if ((lane & 1) == 0 && rloc < 8) {
      z2h[(size_t)(n0 + rloc) * 32 + ct * 8 + (mrow >> 1)] = pack_f16x2(v, vOdd);
    }
  }
}

// ---------------- agg_out: out = z2[n] + sum z2[adj] + b2 (grouped gather) ----
// 128B rows: 8 groups x 8 lanes x 16B. One dwordx4 load = 8 neighbors' rows.
__global__ __launch_bounds__(256, 8) void agg_out(
    const uint32_t* __restrict__ z2h, const int* __restrict__ adj,
    const int* __restrict__ cnt, const float* __restrict__ b2,
    const uint32_t* __restrict__ zpad, float* __restrict__ out) {
  const int lane = threadIdx.x & 63;
  const int wid  = threadIdx.x >> 6;
  const int pp = blockIdx.x * 4 + wid;   // 6250 blocks
  const int nA = pp * 2, nB = pp * 2 + 1;
  const int g8 = lane >> 3;   // neighbor group 0..7
  const int f8 = lane & 7;    // 16B chunk within 128B row

  const uint4* zq = reinterpret_cast<const uint4*>(zpad);

  const int vaA = adj[(size_t)nA * kCap + lane];
  const int vaB = adj[(size_t)nB * kCap + lane];
  int dA = __builtin_amdgcn_readfirstlane(cnt[nA]); if (dA > kCap) dA = kCap;
  int dB = __builtin_amdgcn_readfirstlane(cnt[nB]); if (dB > kCap) dB = kCap;
  const int dm = (dA > dB) ? dA : dB;

  uint32_t aA[4], aB[4];
  {
    const uint4* pa = (g8 == 0) ? reinterpret_cast<const uint4*>(z2h + (size_t)nA * 32) : zq;
    const uint4* pb = (g8 == 0) ? reinterpret_cast<const uint4*>(z2h + (size_t)nB * 32) : zq;
    const uint4 va = pa[f8];
    const uint4 vb = pb[f8];
    aA[0] = va.x; aA[1] = va.y; aA[2] = va.z; aA[3] = va.w;
    aB[0] = vb.x; aB[1] = vb.y; aB[2] = vb.z; aB[3] = vb.w;
  }

  for (int e = 0; e < dm; e += 16) {
    uint4 lA[2], lB[2];
#pragma unroll
    for (int j = 0; j < 2; ++j) {
      const int sl = e + j * 8 + g8;
      const int ia = __shfl(vaA, sl);
      const uint4* pa = (sl < dA) ? reinterpret_cast<const uint4*>(z2h + (size_t)ia * 32) : zq;
      lA[j] = pa[f8];
    }
#pragma unroll
    for (int j = 0; j < 2; ++j) {
      const int sl = e + j * 8 + g8;
      const int ib = __shfl(vaB, sl);
      const uint4* pb = (sl < dB) ? reinterpret_cast<const uint4*>(z2h + (size_t)ib * 32) : zq;
      lB[j] = pb[f8];
    }
#pragma unroll
    for (int j = 0; j < 2; ++j) {
      pk_acc(aA[0], lA[j].x); pk_acc(aA[1], lA[j].y);
      pk_acc(aA[2], lA[j].z); pk_acc(aA[3], lA[j].w);
      pk_acc(aB[0], lB[j].x); pk_acc(aB[1], lB[j].y);
      pk_acc(aB[2], lB[j].z); pk_acc(aB[3], lB[j].w);
    }
  }

  // cross-group reduce over 8 groups (lane bits 3,4,5)
#pragma unroll
  for (int c = 0; c < 4; ++c) {
    uint32_t t;
    t = (uint32_t)__shfl_xor((int)aA[c], 8);  pk_acc(aA[c], t);
    t = (uint32_t)__shfl_xor((int)aA[c], 16); pk_acc(aA[c], t);
    t = (uint32_t)__shfl_xor((int)aA[c], 32); pk_acc(aA[c], t);
    t = (uint32_t)__shfl_xor((int)aB[c], 8);  pk_acc(aB[c], t);
    t = (uint32_t)__shfl_xor((int)aB[c], 16); pk_acc(aB[c], t);
    t = (uint32_t)__shfl_xor((int)aB[c], 32); pk_acc(aB[c], t);
  }

  // lane owns row-dword d = 4*f8 + (g8&3); groups 4..7 are redundant copies
  const int d = 4 * f8 + (g8 & 3);
  const uint32_t mA = (g8 & 2) ? ((g8 & 1) ? aA[3] : aA[2]) : ((g8 & 1) ? aA[1] : aA[0]);
  const uint32_t mB = (g8 & 2) ? ((g8 & 1) ? aB[3] : aB[2]) : ((g8 & 1) ? aB[1] : aB[0]);
  if (g8 < 4) {
    const float2 bb2 = *reinterpret_cast<const float2*>(b2 + 2 * d);
    PairU sA; sA.u = mA;
    float2 oA; oA.x = f16_lo(sA.h) + bb2.x; oA.y = f16_hi(sA.h) + bb2.y;
    *reinterpret_cast<float2*>(out + (size_t)nA * 64 + 2 * d) = oA;
    PairU sB; sB.u = mB;
    float2 oB; oB.x = f16_lo(sB.h) + bb2.x; oB.y = f16_hi(sB.h) + bb2.y;
    *reinterpret_cast<float2*>(out + (size_t)nB * 64 + 2 * d) = oB;
  }
}

// ---------------- launch ----------------
extern "C" void kernel_launch(void* const* d_in, const int* in_sizes, int n_in,
                              void* d_out, int out_size, void* d_ws, size_t ws_size,
                              hipStream_t stream) {
  const float* x  = (const float*)d_in[0];
  const int*   ei = (const int*)d_in[1];
  const float* W1 = (const float*)d_in[2];
  const float* b1 = (const float*)d_in[3];
  const float* W2 = (const float*)d_in[4];
  const float* b2 = (const float*)d_in[5];
  float* out = (float*)d_out;

  const int E = in_sizes[1] / 2;  // edge_index is (2, E), int32 on device
  const int* src = ei;
  const int* dst = ei + E;

  // d_ws layout:
  uint32_t* zpad = (uint32_t*)d_ws;                        // 64 dwords = 256 B, zeroed
  int*      cnt  = (int*)((char*)d_ws + 256);              // 50000 ints
  int*      adj  = cnt + kN;                               // 50000*64 ints = 12.8 MB
  uint32_t* z1h  = (uint32_t*)(adj + (size_t)kN * kCap);   // 50000*64 dwords = 12.8 MB
  uint32_t* z2h  = z1h + (size_t)kN * 64;                  // 50000*32 dwords = 6.4 MB
  uint32_t* W2T  = z2h + (size_t)kN * 32;                  // 4096 dwords = 16 KB

  const int adjBlocks = (E + 1023) / 1024;  // 4 edges/thread

  hipMemsetAsync(d_ws, 0, 256 + (size_t)kN * sizeof(int), stream);  // zpad + cnt
  k1_adj_w2t_gemm1<<<adjBlocks + kW2TBlocks + kGemm1Blocks, 256, 0, stream>>>(
      x, W1, W2, W2T, src, dst, cnt, adj, E, adjBlocks, z1h);
  agg1_gemm2<<<6250, 256, 0, stream>>>(
      z1h, adj, cnt, b1, zpad, W2T, z2h);
  agg_out<<<6250, 256, 0, stream>>>(
      z2h, adj, cnt, b2, zpad, out);
}

// Round 6
// 172.195 us; speedup vs baseline: 1.4752x; 1.0353x over previous
//
#include <hip/hip_runtime.h>
#include <stdint.h>

static constexpr int kN   = 50000;   // nodes
static constexpr int kCap = 64;      // adjacency capacity per node (Poisson(12) tail @64 ~ 1e-25)
static constexpr int kRowB = 192;    // adjacency row bytes: [cnt:int][64 x u16 slots][pad] (3 lines)
static constexpr int kW2TBlocks = 16;    // 16*256 = 4096 = W2T dwords
static constexpr int kGemm1Blocks = 1564;  // 782 rb-groups x 2 cg

typedef __attribute__((ext_vector_type(8))) _Float16 f16x8;  // MFMA A/B fragment
typedef __attribute__((ext_vector_type(2))) _Float16 f16x2;  // packed pair -> v_pk_add_f16
typedef __attribute__((ext_vector_type(4))) float f32x4;     // MFMA 16x16 accumulator

// ---------------- threefry2x32-20 (verified vs Random123 KAT) ----------------
__device__ __forceinline__ uint32_t rotl32(uint32_t v, uint32_t r) {
  return (v << r) | (v >> (32u - r));
}

__device__ __forceinline__ uint2 threefry2x32(uint32_t k0, uint32_t k1,
                                              uint32_t x0, uint32_t x1) {
  const uint32_t k2 = k0 ^ k1 ^ 0x1BD11BDAu;
  x0 += k0; x1 += k1;
#define TFR(r) { x0 += x1; x1 = rotl32(x1, r); x1 ^= x0; }
  TFR(13u) TFR(15u) TFR(26u) TFR(6u)
  x0 += k1; x1 += k2 + 1u;
  TFR(17u) TFR(29u) TFR(16u) TFR(24u)
  x0 += k2; x1 += k0 + 2u;
  TFR(13u) TFR(15u) TFR(26u) TFR(6u)
  x0 += k0; x1 += k1 + 3u;
  TFR(17u) TFR(29u) TFR(16u) TFR(24u)
  x0 += k1; x1 += k2 + 4u;
  TFR(13u) TFR(15u) TFR(26u) TFR(6u)
  x0 += k2; x1 += k0 + 5u;
#undef TFR
  return make_uint2(x0, x1);
}

__device__ __forceinline__ bool drop_elem(uint32_t j) {
  const uint2 r = threefry2x32(0u, 42u, 0u, j);
  return ((r.x ^ r.y) >> 31) != 0u;
}

// ---------------- f16 pack/unpack ----------------
union PairU { f16x2 h; uint32_t u; };
__device__ __forceinline__ uint32_t pack_f16x2(float lo, float hi) {
  PairU p; p.h[0] = (_Float16)lo; p.h[1] = (_Float16)hi; return p.u;
}
__device__ __forceinline__ float f16_lo(f16x2 v) { return (float)v[0]; }
__device__ __forceinline__ float f16_hi(f16x2 v) { return (float)v[1]; }

__device__ __forceinline__ void pk_acc(uint32_t& acc, uint32_t v) {
  PairU a, b; a.u = acc; b.u = v; a.h += b.h; acc = a.u;
}

union FragU { uint4 q; f16x8 f; };

// ---------------- K1: adj-build | W2T-pack | gemm1 (block-range split) ----------------
// Adjacency row per node (192 B, line-aligned): cnt int at +0, u16 slots at +4.
// The atomic and the subsequent slot store hit the SAME cache line (for d<=30),
// eliminating cnt false-sharing (1 node/line vs 16) and halving scatter lines.
__global__ __launch_bounds__(256, 8) void k1_adj_w2t_gemm1(
    const float* __restrict__ x, const float* __restrict__ W1,
    const float* __restrict__ W2, uint32_t* __restrict__ W2T,
    const int* __restrict__ src, const int* __restrict__ dst,
    uint8_t* __restrict__ adjr, int E, int adjBlocks,
    uint32_t* __restrict__ z1h) {
  __shared__ uint32_t WT[64 * 64];  // 16 KB, fragment-major (gemm1 region only)

  if (blockIdx.x < adjBlocks) {
    const int base = blockIdx.x * 1024 + threadIdx.x;
    int d[4], s[4];
    bool ok[4];
#pragma unroll
    for (int j = 0; j < 4; ++j) {
      const int e = base + j * 256;
      ok[j] = (e < E);
      d[j] = ok[j] ? dst[e] : 0;
      s[j] = ok[j] ? src[e] : 0;
    }
    int slot[4];
#pragma unroll
    for (int j = 0; j < 4; ++j)
      slot[j] = ok[j] ? atomicAdd((int*)(adjr + (size_t)d[j] * kRowB), 1) : kCap;
#pragma unroll
    for (int j = 0; j < 4; ++j)
      if (ok[j] && slot[j] < kCap)
        *(uint16_t*)(adjr + (size_t)d[j] * kRowB + 4 + 2 * slot[j]) = (uint16_t)s[j];
    return;
  }

  if (blockIdx.x < adjBlocks + kW2TBlocks) {
    const int w = (blockIdx.x - adjBlocks) * 256 + threadIdx.x;  // < 4096
    const int n = w >> 6, i = w & 63;
    W2T[w] = pack_f16x2(W2[(size_t)(2 * i) * 64 + n], W2[(size_t)(2 * i + 1) * 64 + n]);
    return;
  }

  // ---- gemm1 region ----
  const int gb = blockIdx.x - adjBlocks - kW2TBlocks;  // 0..1563
  const int cg = gb & 1;                               // column group: cols cg*64..+63

  // Stage this cg's half of W1, fragment-major (conflict-free B-fragment reads).
  for (int v = threadIdx.x; v < 64 * 64; v += 256) {
    const int i  = v >> 6;        // k-pair index 0..63
    const int nl = v & 63;        // local column 0..63
    const int kb = i >> 4, r = i & 15;
    const int quad_s = r >> 2, c = r & 3;
    const int ct = nl >> 4, mrow_s = nl & 15;
    const int n = cg * 64 + nl;
    WT[((ct * 4 + kb) * 4 + quad_s) * 64 + mrow_s * 4 + c] =
        pack_f16x2(W1[(size_t)(2 * i) * 128 + n], W1[(size_t)(2 * i + 1) * 128 + n]);
  }
  __syncthreads();

  const int lane = threadIdx.x & 63;
  const int wid  = threadIdx.x >> 6;
  const int rb   = (gb >> 1) * 4 + wid;  // -> rb 0..3127
  if (rb >= 3125) return;                // tail wave (after barrier)
  const int n0   = rb * 16;
  const int quad = lane >> 4;
  const int mrow = lane & 15;

  const float* xp = x + (size_t)(n0 + mrow) * 128 + quad * 8;
  f32x4 acc[4] = {{0.f,0.f,0.f,0.f},{0.f,0.f,0.f,0.f},{0.f,0.f,0.f,0.f},{0.f,0.f,0.f,0.f}};

#pragma unroll
  for (int kb = 0; kb < 4; ++kb) {
    const float4 lo = *reinterpret_cast<const float4*>(xp + kb * 32);
    const float4 hi = *reinterpret_cast<const float4*>(xp + kb * 32 + 4);
    FragU a;
    a.q = make_uint4(pack_f16x2(lo.x, lo.y), pack_f16x2(lo.z, lo.w),
                     pack_f16x2(hi.x, hi.y), pack_f16x2(hi.z, hi.w));
#pragma unroll
    for (int ct = 0; ct < 4; ++ct) {
      FragU b;
      b.q = *reinterpret_cast<const uint4*>(&WT[((ct * 4 + kb) * 4 + quad) * 64 + mrow * 4]);
      acc[ct] = __builtin_amdgcn_mfma_f32_16x16x32_f16(a.f, b.f, acc[ct], 0, 0, 0);
    }
  }

#pragma unroll
  for (int ct = 0; ct < 4; ++ct) {
#pragma unroll
    for (int r = 0; r < 4; ++r) {
      const float v = acc[ct][r];
      const float vOdd = __shfl(v, lane | 1);
      if ((lane & 1) == 0) {
        const int row = n0 + quad * 4 + r;
        z1h[(size_t)row * 64 + cg * 32 + ct * 8 + (mrow >> 1)] = pack_f16x2(v, vOdd);
      }
    }
  }
}

// ---------------- K2: agg1 (grouped dwordx4 gather) + gemm2 fused ----------------
// 2 nodes/wave. Lane = (group g=lane>>4, chunk fl=lane&15): one dwordx4 load
// covers 4 neighbors' full 256B rows. Adjacency from the u16 row (half bytes).
__global__ __launch_bounds__(256, 8) void agg1_gemm2(
    const uint32_t* __restrict__ z1h, const uint8_t* __restrict__ adjr,
    const float* __restrict__ b1,
    const uint32_t* __restrict__ zpad, const uint32_t* __restrict__ W2T,
    uint32_t* __restrict__ z2h) {
  __shared__ uint32_t WT[64 * 68];  // 17.4 KB W2 packed
  __shared__ uint32_t HT[8 * 68];   // 2.2 KB h-tile (8 rows/block)

  // Stage W2T linearly (conflict-free); consumed only after the post-agg barrier.
  for (int v = threadIdx.x; v < 64 * 64; v += 256)
    WT[(v >> 6) * 68 + (v & 63)] = W2T[v];

  const int lane = threadIdx.x & 63;
  const int wid  = threadIdx.x >> 6;
  const int n0   = blockIdx.x * 8;       // 6250 blocks * 8 nodes
  const int nA = n0 + 2 * wid, nB = nA + 1;
  const int g  = lane >> 4;   // neighbor group 0..3
  const int fl = lane & 15;   // 16B chunk within 256B row

  const uint4* zq = reinterpret_cast<const uint4*>(zpad);

  const uint8_t* rowA = adjr + (size_t)nA * kRowB;
  const uint8_t* rowB = adjr + (size_t)nB * kRowB;
  const int vaA = *(const uint16_t*)(rowA + 4 + 2 * lane);
  const int vaB = *(const uint16_t*)(rowB + 4 + 2 * lane);
  int dA = __builtin_amdgcn_readfirstlane(*(const int*)rowA); if (dA > kCap) dA = kCap;
  int dB = __builtin_amdgcn_readfirstlane(*(const int*)rowB); if (dB > kCap) dB = kCap;
  const int dm = (dA > dB) ? dA : dB;

  uint32_t aA[4], aB[4];
  {  // self: group 0 loads the node's own row, other groups read zeroed pad
    const uint4* pa = (g == 0) ? reinterpret_cast<const uint4*>(z1h + (size_t)nA * 64) : zq;
    const uint4* pb = (g == 0) ? reinterpret_cast<const uint4*>(z1h + (size_t)nB * 64) : zq;
    const uint4 va = pa[fl];
    const uint4 vb = pb[fl];
    aA[0] = va.x; aA[1] = va.y; aA[2] = va.z; aA[3] = va.w;
    aB[0] = vb.x; aB[1] = vb.y; aB[2] = vb.z; aB[3] = vb.w;
  }

  for (int e = 0; e < dm; e += 16) {
    uint4 lA[4], lB[4];
#pragma unroll
    for (int j = 0; j < 4; ++j) {
      const int sl = e + j * 4 + g;                 // neighbor slot for this lane
      const int ia = __shfl(vaA, sl);               // one bpermute distributes 4 ids
      const uint4* pa = (sl < dA) ? reinterpret_cast<const uint4*>(z1h + (size_t)ia * 64) : zq;
      lA[j] = pa[fl];
    }
#pragma unroll
    for (int j = 0; j < 4; ++j) {
      const int sl = e + j * 4 + g;
      const int ib = __shfl(vaB, sl);
      const uint4* pb = (sl < dB) ? reinterpret_cast<const uint4*>(z1h + (size_t)ib * 64) : zq;
      lB[j] = pb[fl];
    }
#pragma unroll
    for (int j = 0; j < 4; ++j) {
      pk_acc(aA[0], lA[j].x); pk_acc(aA[1], lA[j].y);
      pk_acc(aA[2], lA[j].z); pk_acc(aA[3], lA[j].w);
      pk_acc(aB[0], lB[j].x); pk_acc(aB[1], lB[j].y);
      pk_acc(aB[2], lB[j].z); pk_acc(aB[3], lB[j].w);
    }
  }

  // cross-group reduce (lanes differing in bits 4/5 = other neighbor groups)
#pragma unroll
  for (int c = 0; c < 4; ++c) {
    uint32_t t;
    t = (uint32_t)__shfl_xor((int)aA[c], 16); pk_acc(aA[c], t);
    t = (uint32_t)__shfl_xor((int)aA[c], 32); pk_acc(aA[c], t);
    t = (uint32_t)__shfl_xor((int)aB[c], 16); pk_acc(aB[c], t);
    t = (uint32_t)__shfl_xor((int)aB[c], 32); pk_acc(aB[c], t);
  }

  // each lane owns row-dword d = 4*fl + g (all 64 dwords covered exactly once)
  const int d = 4 * fl + g;
  const uint32_t mA = (g & 2) ? ((g & 1) ? aA[3] : aA[2]) : ((g & 1) ? aA[1] : aA[0]);
  const uint32_t mB = (g & 2) ? ((g & 1) ? aB[3] : aB[2]) : ((g & 1) ? aB[1] : aB[0]);
  const float2 bb2 = *reinterpret_cast<const float2*>(b1 + 2 * d);
  {
    PairU s; s.u = mA;
    float hx = fmaxf(f16_lo(s.h) + bb2.x, 0.0f);
    float hy = fmaxf(f16_hi(s.h) + bb2.y, 0.0f);
    const uint32_t j0 = (uint32_t)nA * 128u + 2u * (uint32_t)d;
    hx = drop_elem(j0)      ? 0.0f : hx * 2.0f;
    hy = drop_elem(j0 + 1u) ? 0.0f : hy * 2.0f;
    HT[(2 * wid) * 68 + d] = pack_f16x2(hx, hy);   // 64 distinct dwords: <=2 lanes/bank
  }
  {
    PairU s; s.u = mB;
    float hx = fmaxf(f16_lo(s.h) + bb2.x, 0.0f);
    float hy = fmaxf(f16_hi(s.h) + bb2.y, 0.0f);
    const uint32_t j0 = (uint32_t)nB * 128u + 2u * (uint32_t)d;
    hx = drop_elem(j0)      ? 0.0f : hx * 2.0f;
    hy = drop_elem(j0 + 1u) ? 0.0f : hy * 2.0f;
    HT[(2 * wid + 1) * 68 + d] = pack_f16x2(hx, hy);
  }
  __syncthreads();

  // ---- gemm2 phase: wave wid computes output cols [wid*16, wid*16+16) for
  // the block's 8 rows. A-fragment rows 8-15 clamped to 0-7 (outputs unwritten).
  const int quad = lane >> 4;
  const int mrow = lane & 15;
  const int ct   = wid;
  f32x4 acc = {0.f, 0.f, 0.f, 0.f};
#pragma unroll
  for (int kb = 0; kb < 4; ++kb) {
    FragU a;
    a.q = *reinterpret_cast<const uint4*>(&HT[(mrow & 7) * 68 + kb * 16 + quad * 4]);
    FragU b;
    b.q = *reinterpret_cast<const uint4*>(&WT[(ct * 16 + mrow) * 68 + kb * 16 + quad * 4]);
    acc = __builtin_amdgcn_mfma_f32_16x16x32_f16(a.f, b.f, acc, 0, 0, 0);
  }
#pragma unroll
  for (int r = 0; r < 4; ++r) {
    const float v = acc[r];
    const float vOdd = __shfl(v, lane | 1);
    const int rloc = quad * 4 + r;                 // D row = quad*4+reg
    if ((lane & 1) == 0 && rloc < 8) {
      z2h[(size_t)(n0 + rloc) * 32 + ct * 8 + (mrow >> 1)] = pack_f16x2(v, vOdd);
    }
  }
}

// ---------------- agg_out: out = z2[n] + sum z2[adj] + b2 (grouped gather) ----
// 128B rows: 8 groups x 8 lanes x 16B. One dwordx4 load = 8 neighbors' rows.
__global__ __launch_bounds__(256, 8) void agg_out(
    const uint32_t* __restrict__ z2h, const uint8_t* __restrict__ adjr,
    const float* __restrict__ b2,
    const uint32_t* __restrict__ zpad, float* __restrict__ out) {
  const int lane = threadIdx.x & 63;
  const int wid  = threadIdx.x >> 6;
  const int pp = blockIdx.x * 4 + wid;   // 6250 blocks
  const int nA = pp * 2, nB = pp * 2 + 1;
  const int g8 = lane >> 3;   // neighbor group 0..7
  const int f8 = lane & 7;    // 16B chunk within 128B row

  const uint4* zq = reinterpret_cast<const uint4*>(zpad);

  const uint8_t* rowA = adjr + (size_t)nA * kRowB;
  const uint8_t* rowB = adjr + (size_t)nB * kRowB;
  const int vaA = *(const uint16_t*)(rowA + 4 + 2 * lane);
  const int vaB = *(const uint16_t*)(rowB + 4 + 2 * lane);
  int dA = __builtin_amdgcn_readfirstlane(*(const int*)rowA); if (dA > kCap) dA = kCap;
  int dB = __builtin_amdgcn_readfirstlane(*(const int*)rowB); if (dB > kCap) dB = kCap;
  const int dm = (dA > dB) ? dA : dB;

  uint32_t aA[4], aB[4];
  {
    const uint4* pa = (g8 == 0) ? reinterpret_cast<const uint4*>(z2h + (size_t)nA * 32) : zq;
    const uint4* pb = (g8 == 0) ? reinterpret_cast<const uint4*>(z2h + (size_t)nB * 32) : zq;
    const uint4 va = pa[f8];
    const uint4 vb = pb[f8];
    aA[0] = va.x; aA[1] = va.y; aA[2] = va.z; aA[3] = va.w;
    aB[0] = vb.x; aB[1] = vb.y; aB[2] = vb.z; aB[3] = vb.w;
  }

  for (int e = 0; e < dm; e += 16) {
    uint4 lA[2], lB[2];
#pragma unroll
    for (int j = 0; j < 2; ++j) {
      const int sl = e + j * 8 + g8;
      const int ia = __shfl(vaA, sl);
      const uint4* pa = (sl < dA) ? reinterpret_cast<const uint4*>(z2h + (size_t)ia * 32) : zq;
      lA[j] = pa[f8];
    }
#pragma unroll
    for (int j = 0; j < 2; ++j) {
      const int sl = e + j * 8 + g8;
      const int ib = __shfl(vaB, sl);
      const uint4* pb = (sl < dB) ? reinterpret_cast<const uint4*>(z2h + (size_t)ib * 32) : zq;
      lB[j] = pb[f8];
    }
#pragma unroll
    for (int j = 0; j < 2; ++j) {
      pk_acc(aA[0], lA[j].x); pk_acc(aA[1], lA[j].y);
      pk_acc(aA[2], lA[j].z); pk_acc(aA[3], lA[j].w);
      pk_acc(aB[0], lB[j].x); pk_acc(aB[1], lB[j].y);
      pk_acc(aB[2], lB[j].z); pk_acc(aB[3], lB[j].w);
    }
  }

  // cross-group reduce over 8 groups (lane bits 3,4,5)
#pragma unroll
  for (int c = 0; c < 4; ++c) {
    uint32_t t;
    t = (uint32_t)__shfl_xor((int)aA[c], 8);  pk_acc(aA[c], t);
    t = (uint32_t)__shfl_xor((int)aA[c], 16); pk_acc(aA[c], t);
    t = (uint32_t)__shfl_xor((int)aA[c], 32); pk_acc(aA[c], t);
    t = (uint32_t)__shfl_xor((int)aB[c], 8);  pk_acc(aB[c], t);
    t = (uint32_t)__shfl_xor((int)aB[c], 16); pk_acc(aB[c], t);
    t = (uint32_t)__shfl_xor((int)aB[c], 32); pk_acc(aB[c], t);
  }

  // lane owns row-dword d = 4*f8 + (g8&3); groups 4..7 are redundant copies
  const int d = 4 * f8 + (g8 & 3);
  const uint32_t mA = (g8 & 2) ? ((g8 & 1) ? aA[3] : aA[2]) : ((g8 & 1) ? aA[1] : aA[0]);
  const uint32_t mB = (g8 & 2) ? ((g8 & 1) ? aB[3] : aB[2]) : ((g8 & 1) ? aB[1] : aB[0]);
  if (g8 < 4) {
    const float2 bb2 = *reinterpret_cast<const float2*>(b2 + 2 * d);
    PairU sA; sA.u = mA;
    float2 oA; oA.x = f16_lo(sA.h) + bb2.x; oA.y = f16_hi(sA.h) + bb2.y;
    *reinterpret_cast<float2*>(out + (size_t)nA * 64 + 2 * d) = oA;
    PairU sB; sB.u = mB;
    float2 oB; oB.x = f16_lo(sB.h) + bb2.x; oB.y = f16_hi(sB.h) + bb2.y;
    *reinterpret_cast<float2*>(out + (size_t)nB * 64 + 2 * d) = oB;
  }
}

// ---------------- launch ----------------
extern "C" void kernel_launch(void* const* d_in, const int* in_sizes, int n_in,
                              void* d_out, int out_size, void* d_ws, size_t ws_size,
                              hipStream_t stream) {
  const float* x  = (const float*)d_in[0];
  const int*   ei = (const int*)d_in[1];
  const float* W1 = (const float*)d_in[2];
  const float* b1 = (const float*)d_in[3];
  const float* W2 = (const float*)d_in[4];
  const float* b2 = (const float*)d_in[5];
  float* out = (float*)d_out;

  const int E = in_sizes[1] / 2;  // edge_index is (2, E), int32 on device
  const int* src = ei;
  const int* dst = ei + E;

  // d_ws layout:
  uint32_t* zpad = (uint32_t*)d_ws;                        // 64 dwords = 256 B, zeroed
  uint8_t*  adjr = (uint8_t*)d_ws + 256;                   // 50000 x 192 B = 9.6 MB
  uint32_t* z1h  = (uint32_t*)(adjr + (size_t)kN * kRowB); // 50000*64 dwords = 12.8 MB
  uint32_t* z2h  = z1h + (size_t)kN * 64;                  // 50000*32 dwords = 6.4 MB
  uint32_t* W2T  = z2h + (size_t)kN * 32;                  // 4096 dwords = 16 KB

  const int adjBlocks = (E + 1023) / 1024;  // 4 edges/thread

  hipMemsetAsync(d_ws, 0, 256 + (size_t)kN * kRowB, stream);  // zpad + adjr (cnt=0)
  k1_adj_w2t_gemm1<<<adjBlocks + kW2TBlocks + kGemm1Blocks, 256, 0, stream>>>(
      x, W1, W2, W2T, src, dst, adjr, E, adjBlocks, z1h);
  agg1_gemm2<<<6250, 256, 0, stream>>>(
      z1h, adjr, b1, zpad, W2T, z2h);
  agg_out<<<6250, 256, 0, stream>>>(
      z2h, adjr, b2, zpad, out);
}